// Round 5
// baseline (742.203 us; speedup 1.0000x reference)
//
#include <hip/hip_runtime.h>
#include <hip/hip_cooperative_groups.h>
#include <math.h>

namespace cg = cooperative_groups;

#define NBINS 4096
#define CAP   4096
#define MAXC  300
#define MAXCP 320
#define NTASK (MAXC*5)
#define TOPN  100
#define NBLK  256
#define NTHR  1024

// Shared box-decode; expression-identical to previous rounds (absmax was 0.0).
__device__ __forceinline__ void decode4(float x1, float y1, float x2, float y2,
                                        float4 d4, float Wimg, float Himg,
                                        float& bx1, float& by1, float& bx2, float& by2)
{
    float w  = x2 - x1 + 1.0f;
    float h  = y2 - y1 + 1.0f;
    float cx = x1 + 0.5f*(w - 1.0f);
    float cy = y1 + 0.5f*(h - 1.0f);
    float d0 = d4.x*0.1f, d1 = d4.y*0.1f, d2 = d4.z*0.2f, d3 = d4.w*0.2f;
    float pcx = d0*w + cx;
    float pcy = d1*h + cy;
    float pw  = expf(d2)*w;
    float ph  = expf(d3)*h;
    bx1 = fminf(fmaxf(pcx - 0.5f*(pw-1.0f), 0.0f), Wimg-1.0f);
    by1 = fminf(fmaxf(pcy - 0.5f*(ph-1.0f), 0.0f), Himg-1.0f);
    bx2 = fminf(fmaxf(pcx + 0.5f*(pw-1.0f), 0.0f), Wimg-1.0f);
    by2 = fminf(fmaxf(pcy + 0.5f*(ph-1.0f), 0.0f), Himg-1.0f);
}

// ============================================================================
// MEGA: all 7 phases in one cooperative kernel. 256 blocks x 1024 threads,
// exactly one ROI-group (4 ROIs) per thread (N = 1e6 -> Ng = 250000 <= 262144).
// Scores live in REGISTERS across grid syncs (scores4 buffer eliminated).
// Phase logic is copied verbatim from the round-4 PASSED kernels.
// ============================================================================
__global__ __launch_bounds__(NTHR)
void rcnn_mega(const float* __restrict__ cls, const float* __restrict__ bbox,
               const float* __restrict__ rois, const float* __restrict__ iminfo,
               char* __restrict__ ws, float* __restrict__ out, int Ng)
{
    // ---- ws layout: identical to the fallback host layout (scores region skipped)
    size_t off = ((size_t)Ng * 16 + 255) & ~(size_t)255;
    unsigned int* hist    = (unsigned int*)(ws + off); off += NBINS*4;
    off += 256;  // taubin slot (fallback only)
    unsigned int* counter = (unsigned int*)(ws + off); off += 256;
    float*  cscore        = (float*)(ws + off);        off += CAP*4;
    int*    cidx          = (int*)(ws + off);          off += CAP*4;
    float4* bxg           = (float4*)(ws + off);       off += MAXCP*16;
    float*  areag         = (float*)(ws + off);        off += ((MAXCP*4 + 255) & ~(size_t)255);
    float*  prg           = (float*)(ws + off);        off += ((MAXC*5*4 + 255) & ~(size_t)255);
    unsigned long long* maskg = (unsigned long long*)(ws + off); off += 256;
    unsigned long long* supg  = (unsigned long long*)(ws + off);

    // ---- LDS: 32 KB union (hist | rank s_s+s_id | scan sup) + small statics ≈ 44 KB
    __shared__ __align__(16) unsigned char u_smem[32768];
    __shared__ __align__(16) float4 bxs[MAXCP];
    __shared__ float ars[MAXCP];
    __shared__ float orows[TOPN*10];
    __shared__ int   kept_list[TOPN];
    __shared__ int   s_misc[2];   // [0]=tau, [1]=kept

    cg::grid_group grid = cg::this_grid();
    const int t   = threadIdx.x;
    const int bid = blockIdx.x;
    const int g   = bid * NTHR + t;

    // ================= phase A: score 4 ROIs/thread (registers) + per-block LDS hist;
    //                  block 0 zero-inits all small global state =================
    unsigned int* lh = (unsigned int*)u_smem;
    for (int k = t; k < NBINS; k += NTHR) lh[k] = 0u;
    if (bid == 0) {
        for (int k = t; k < NBINS; k += NTHR) hist[k] = 0u;
        if (t == 0) *counter = 0u;
        if (t < 5)  maskg[t] = 0ull;
        for (int r = t; r < MAXCP; r += NTHR) {
            bxg[r] = make_float4(0.0f, 0.0f, 0.0f, 0.0f);
            areag[r] = 0.0f;
        }
    }
    __syncthreads();   // lh zeroed before LDS atomics

    float s[4] = { -1.0f, -1.0f, -1.0f, -1.0f };
    if (g < Ng) {
        const float4* cls4  = (const float4*)cls;
        const float4* rois4 = (const float4*)rois;
        const float4* bbox4 = (const float4*)bbox;
        float c[20], q[20];
        #pragma unroll
        for (int v = 0; v < 5; v++) {
            float4 cv = cls4[5*g + v];
            c[4*v] = cv.x; c[4*v+1] = cv.y; c[4*v+2] = cv.z; c[4*v+3] = cv.w;
            float4 rv = rois4[5*g + v];
            q[4*v] = rv.x; q[4*v+1] = rv.y; q[4*v+2] = rv.z; q[4*v+3] = rv.w;
        }
        float Himg = iminfo[0], Wimg = iminfo[1];
        #pragma unroll
        for (int j = 0; j < 4; j++) {
            float p0 = c[5*j], p1 = c[5*j+1], p2 = c[5*j+2], p3 = c[5*j+3], p4 = c[5*j+4];
            float m = p1; int a = 1;
            if (p2 > m) { m = p2; a = 2; }
            if (p3 > m) { m = p3; a = 3; }
            if (p4 > m) { m = p4; a = 4; }
            float sc = -1.0f;
            if (((1.0f - p0) >= 0.2f) && (m > 0.1f)) {
                float4 d4 = bbox4[20*g + 5*j + a];
                float bx1, by1, bx2, by2;
                decode4(q[5*j+1], q[5*j+2], q[5*j+3], q[5*j+4], d4, Wimg, Himg, bx1, by1, bx2, by2);
                float bw = bx2 - bx1 + 1.0f;
                float bh = by2 - by1 + 1.0f;
                if ((bw >= 6.0f) || (bh >= 6.0f)) sc = m;
            }
            s[j] = sc;
            if (sc > -0.5f) {
                int bin = (int)(sc * (float)NBINS);
                bin = bin > NBINS-1 ? NBINS-1 : bin;
                atomicAdd(&lh[bin], 1u);
            }
        }
    }
    __threadfence();
    grid.sync();   // sync1: global hist zeroed everywhere + all lh complete

    // ================= phase B: flush LDS hist -> global (skip zeros) =================
    for (int k = t; k < NBINS; k += NTHR) {
        unsigned int v = lh[k];
        if (v) atomicAdd(&hist[k], v);
    }
    __threadfence();
    grid.sync();   // sync2: global hist complete

    // ================= phase D: tau (redundant per-block, wave 0) + compact =================
    // tau = largest bin with suffix >= MAXC; bit-identical to the proven rcnn_pass2.
    if (t < 64) {
        const uint4* h4 = (const uint4*)hist;
        uint4 v[16];
        #pragma unroll
        for (int j = 0; j < 16; j++) v[j] = h4[t*16 + j];
        unsigned int chunk = 0;
        #pragma unroll
        for (int j = 0; j < 16; j++) chunk += v[j].x + v[j].y + v[j].z + v[j].w;
        unsigned int sfx = chunk;
        #pragma unroll
        for (int d = 1; d < 64; d <<= 1) {
            unsigned int o = __shfl_down(sfx, d, 64);
            if (t + d < 64) sfx += o;
        }
        unsigned int nxt = sfx - chunk;
        bool found = (sfx >= MAXC) && (nxt < MAXC);
        unsigned long long bal = __ballot(found);
        if (found) {
            unsigned int cum = nxt;
            int tauv = 64*t;
            #pragma unroll
            for (int k = 15; k >= 0; k--) {
                cum += v[k].w; if (cum >= MAXC) { tauv = 64*t + 4*k + 3; goto dtau; }
                cum += v[k].z; if (cum >= MAXC) { tauv = 64*t + 4*k + 2; goto dtau; }
                cum += v[k].y; if (cum >= MAXC) { tauv = 64*t + 4*k + 1; goto dtau; }
                cum += v[k].x; if (cum >= MAXC) { tauv = 64*t + 4*k + 0; goto dtau; }
            }
            dtau:
            s_misc[0] = tauv;
        }
        if (bal == 0ull && t == 0) s_misc[0] = 0;
    }
    __syncthreads();
    {
        int tau = s_misc[0];
        if (g < Ng) {
            #pragma unroll
            for (int j = 0; j < 4; j++) {
                float sc = s[j];
                if (sc > -0.5f) {
                    int bin = (int)(sc * (float)NBINS);
                    bin = bin > NBINS-1 ? NBINS-1 : bin;
                    if (bin >= tau) {
                        unsigned int pos = atomicAdd(counter, 1u);
                        if (pos < CAP) { cscore[pos] = sc; cidx[pos] = 4*g + j; }
                    }
                }
            }
        }
    }
    __threadfence();
    grid.sync();   // sync3: candidate list complete

    // ================= phase E+F: distributed exact stable rank + inline decode =================
    {
        float* s_s  = (float*)u_smem;            // hist (lh) dead; reuse union
        int*   s_id = (int*)(u_smem + CAP*4);
        int M = (int)*counter; if (M > CAP) M = CAP;
        for (int i = t; i < M; i += NTHR) { s_s[i] = cscore[i]; s_id[i] = cidx[i]; }
        __syncthreads();

        int C = (M + NBLK - 1) / NBLK;           // candidates per block
        float Himg = iminfo[0], Wimg = iminfo[1];
        const float4* sv = (const float4*)s_s;
        const int4*   dv = (const int4*)s_id;
        int M4 = M >> 2;
        for (int ii = t; ii < C; ii += NTHR) {
            int i = bid * C + ii;
            if (i < M) {
                float si = s_s[i]; int di = s_id[i];
                int r = 0;
                for (int jj = 0; jj < M4; jj++) {
                    float4 sj = sv[jj]; int4 dj = dv[jj];
                    r += (sj.x > si) || (sj.x == si && dj.x < di);
                    r += (sj.y > si) || (sj.y == si && dj.y < di);
                    r += (sj.z > si) || (sj.z == si && dj.z < di);
                    r += (sj.w > si) || (sj.w == si && dj.w < di);
                }
                for (int j = M4 << 2; j < M; j++) {
                    float sj = s_s[j]; int dj = s_id[j];
                    r += (sj > si) || (sj == si && dj < di);
                }
                if (r < MAXC) {
                    // decode candidate di into output row r (no sync needed: same owner)
                    int idx = di;
                    float p0 = cls[5*idx], p1 = cls[5*idx+1], p2 = cls[5*idx+2],
                          p3 = cls[5*idx+3], p4 = cls[5*idx+4];
                    prg[5*r+0]=p0; prg[5*r+1]=p1; prg[5*r+2]=p2; prg[5*r+3]=p3; prg[5*r+4]=p4;
                    float m = p1; int a = 1;
                    if (p2 > m) { m = p2; a = 2; }
                    if (p3 > m) { m = p3; a = 3; }
                    if (p4 > m) { m = p4; a = 4; }
                    float4 d4 = ((const float4*)bbox)[5*idx + a];
                    float bx1, by1, bx2, by2;
                    decode4(rois[5*idx+1], rois[5*idx+2], rois[5*idx+3], rois[5*idx+4],
                            d4, Wimg, Himg, bx1, by1, bx2, by2);
                    bxg[r] = make_float4(bx1, by1, bx2, by2);
                    areag[r] = (bx2-bx1)*(by2-by1);
                    atomicOr(&maskg[r>>6], 1ull << (r & 63));
                }
            }
        }
    }
    __threadfence();
    grid.sync();   // sync4: boxes/areas/probs/mask complete

    // ================= phase G: suppression bitmask matrix (6 tasks/block) =================
    {
        for (int r = t; r < MAXCP; r += NTHR) { bxs[r] = bxg[r]; ars[r] = areag[r]; }
        __syncthreads();
        if (t < 6) {
            int task = bid * 6 + t;
            if (task < NTASK) {
                int w = task / MAXC;
                int i = task - w * MAXC;
                unsigned long long bits = 0ull;
                int j0 = w << 6;
                if (j0 + 63 > i) {
                    float4 bi = bxs[i];
                    float areaA = ars[i];
                    // IEEE division kept: bit-exact keep-mask vs the JAX reference.
                    for (int b = 0; b < 64; b++) {
                        int j = j0 + b;
                        float4 bj = bxs[j];
                        float lx = fmaxf(bi.x, bj.x), ly = fmaxf(bi.y, bj.y);
                        float rx = fminf(bi.z, bj.z), ry = fminf(bi.w, bj.w);
                        float iw = fmaxf(rx - lx, 0.0f), ih = fmaxf(ry - ly, 0.0f);
                        float inter = iw * ih;
                        float iou = inter / (areaA + ars[j] - inter);  // NaN/neg-safe
                        bits |= (iou > 0.5f) ? (1ull << b) : 0ull;
                    }
                    unsigned long long jgt = (i < j0) ? ~0ull
                                          : ((i - j0) >= 63 ? 0ull : ~((1ull << (i - j0 + 1)) - 1ull));
                    bits &= jgt & maskg[w];
                }
                supg[i*6 + w] = bits;
            }
        }
    }
    __threadfence();
    grid.sync();   // sync5: sup matrix complete

    // ================= phase H: block 0 serial ctz scan (early-stop) + output =================
    if (bid == 0) {
        unsigned long long* sup = (unsigned long long*)u_smem;  // rank LDS dead; reuse
        const ulonglong2* sg2 = (const ulonglong2*)supg;
        ulonglong2* sl2 = (ulonglong2*)sup;
        for (int k = t; k < (MAXC*6)/2; k += NTHR) sl2[k] = sg2[k];
        for (int k = t; k < TOPN*10; k += NTHR) orows[k] = 0.0f;
        __syncthreads();

        if (t == 0) {
            unsigned long long k0=maskg[0], k1=maskg[1], k2=maskg[2], k3=maskg[3], k4=maskg[4];
            int kept = 0;
            #define SCAN_WORD(W, KW)                                                   \
            if (kept < TOPN) {                                                         \
                unsigned long long donem = 0ull;                                       \
                for (;;) {                                                             \
                    unsigned long long rem = (KW) & ~donem;                            \
                    if (!rem) break;                                                   \
                    int b = __builtin_ctzll(rem);                                      \
                    int i = (W << 6) + b;                                              \
                    kept_list[kept++] = i;                                             \
                    if (kept >= TOPN) break;                                           \
                    unsigned long long s0 = sup[i*6+0], s1 = sup[i*6+1],               \
                                       s2 = sup[i*6+2], s3 = sup[i*6+3],               \
                                       s4 = sup[i*6+4];                                \
                    k0 &= ~s0; k1 &= ~s1; k2 &= ~s2; k3 &= ~s3; k4 &= ~s4;             \
                    donem = (b == 63) ? ~0ull : ((2ull << b) - 1ull);                  \
                }                                                                      \
            }
            SCAN_WORD(0, k0)
            SCAN_WORD(1, k1)
            SCAN_WORD(2, k2)
            SCAN_WORD(3, k3)
            SCAN_WORD(4, k4)
            #undef SCAN_WORD
            s_misc[1] = kept;
        }
        __syncthreads();

        int kept = s_misc[1];
        if (t < kept) {
            int r = kept_list[t];
            float4 bx = bxg[r];
            float* row = &orows[t*10];
            row[0] = 0.0f;
            row[1] = bx.x; row[2] = bx.y; row[3] = bx.z; row[4] = bx.w;
            row[5] = prg[5*r+0]; row[6] = prg[5*r+1]; row[7] = prg[5*r+2];
            row[8] = prg[5*r+3]; row[9] = prg[5*r+4];
        }
        __syncthreads();
        for (int k = t; k < TOPN*10; k += NTHR) out[k] = orows[k];
    }
}

// ============================================================================
// FALLBACK: the proven round-4 7-kernel pipeline (verbatim), used only if the
// cooperative launch is rejected by the runtime/capture.
// ============================================================================
__global__ __launch_bounds__(256)
void rcnn_pass1(const float4* __restrict__ cls4, const float4* __restrict__ bbox4,
                const float4* __restrict__ rois4, const float* __restrict__ iminfo,
                float4* __restrict__ scores4,
                unsigned int* __restrict__ hist, unsigned int* __restrict__ counter, int Ng)
{
    if (blockIdx.x == 0) {
        for (int k = threadIdx.x; k < NBINS; k += 256) hist[k] = 0u;
        if (threadIdx.x == 0) *counter = 0u;
    }
    int g = blockIdx.x * blockDim.x + threadIdx.x;
    if (g >= Ng) return;
    float c[20], q[20];
    #pragma unroll
    for (int v = 0; v < 5; v++) {
        float4 cv = cls4[5*g + v];
        c[4*v] = cv.x; c[4*v+1] = cv.y; c[4*v+2] = cv.z; c[4*v+3] = cv.w;
        float4 rv = rois4[5*g + v];
        q[4*v] = rv.x; q[4*v+1] = rv.y; q[4*v+2] = rv.z; q[4*v+3] = rv.w;
    }
    float Himg = iminfo[0], Wimg = iminfo[1];
    float s[4];
    #pragma unroll
    for (int j = 0; j < 4; j++) {
        float p0 = c[5*j], p1 = c[5*j+1], p2 = c[5*j+2], p3 = c[5*j+3], p4 = c[5*j+4];
        float m = p1; int a = 1;
        if (p2 > m) { m = p2; a = 2; }
        if (p3 > m) { m = p3; a = 3; }
        if (p4 > m) { m = p4; a = 4; }
        float sc = -1.0f;
        if (((1.0f - p0) >= 0.2f) && (m > 0.1f)) {
            float4 d4 = bbox4[20*g + 5*j + a];
            float bx1, by1, bx2, by2;
            decode4(q[5*j+1], q[5*j+2], q[5*j+3], q[5*j+4], d4, Wimg, Himg, bx1, by1, bx2, by2);
            float bw = bx2 - bx1 + 1.0f;
            float bh = by2 - by1 + 1.0f;
            if ((bw >= 6.0f) || (bh >= 6.0f)) sc = m;
        }
        s[j] = sc;
    }
    scores4[g] = make_float4(s[0], s[1], s[2], s[3]);
}

__global__ __launch_bounds__(1024)
void rcnn_hist(const float4* __restrict__ scores4, unsigned int* __restrict__ hist, int Ng)
{
    __shared__ unsigned int lh[NBINS];
    const int t = threadIdx.x;
    for (int k = t; k < NBINS; k += 1024) lh[k] = 0u;
    __syncthreads();
    int stride = gridDim.x * 1024;
    for (int g = blockIdx.x * 1024 + t; g < Ng; g += stride) {
        float4 s4 = scores4[g];
        float ss[4] = { s4.x, s4.y, s4.z, s4.w };
        #pragma unroll
        for (int j = 0; j < 4; j++) {
            float s = ss[j];
            if (s > -0.5f) {
                int bin = (int)(s * (float)NBINS);
                bin = bin > NBINS-1 ? NBINS-1 : bin;
                atomicAdd(&lh[bin], 1u);
            }
        }
    }
    __syncthreads();
    for (int k = t; k < NBINS; k += 1024) {
        unsigned int v = lh[k];
        if (v) atomicAdd(&hist[k], v);
    }
}

__global__ __launch_bounds__(64)
void rcnn_pass2(const unsigned int* __restrict__ hist, int* __restrict__ taubin)
{
    const int t = threadIdx.x;
    const uint4* h4 = (const uint4*)hist;
    uint4 v[16];
    #pragma unroll
    for (int j = 0; j < 16; j++) v[j] = h4[t*16 + j];
    unsigned int chunk = 0;
    #pragma unroll
    for (int j = 0; j < 16; j++) chunk += v[j].x + v[j].y + v[j].z + v[j].w;
    unsigned int sfx = chunk;
    #pragma unroll
    for (int d = 1; d < 64; d <<= 1) {
        unsigned int o = __shfl_down(sfx, d, 64);
        if (t + d < 64) sfx += o;
    }
    unsigned int nxt = sfx - chunk;
    bool found = (sfx >= MAXC) && (nxt < MAXC);
    unsigned long long bal = __ballot(found);
    if (found) {
        unsigned int cum = nxt;
        int tau = 64*t;
        #pragma unroll
        for (int k = 15; k >= 0; k--) {
            cum += v[k].w; if (cum >= MAXC) { tau = 64*t + 4*k + 3; goto done; }
            cum += v[k].z; if (cum >= MAXC) { tau = 64*t + 4*k + 2; goto done; }
            cum += v[k].y; if (cum >= MAXC) { tau = 64*t + 4*k + 1; goto done; }
            cum += v[k].x; if (cum >= MAXC) { tau = 64*t + 4*k + 0; goto done; }
        }
        done:
        *taubin = tau;
    }
    if (bal == 0ull && t == 0) *taubin = 0;
}

__global__ __launch_bounds__(256)
void rcnn_pass3(const float4* __restrict__ scores4, const int* __restrict__ taubin,
                float* __restrict__ cscore, int* __restrict__ cidx,
                unsigned int* __restrict__ counter, int Ng)
{
    int g = blockIdx.x * blockDim.x + threadIdx.x;
    if (g >= Ng) return;
    float4 s4 = scores4[g];
    int tau = *taubin;
    float ss[4] = { s4.x, s4.y, s4.z, s4.w };
    #pragma unroll
    for (int j = 0; j < 4; j++) {
        float s = ss[j];
        if (s > -0.5f) {
            int bin = (int)(s * (float)NBINS);
            bin = bin > NBINS-1 ? NBINS-1 : bin;
            if (bin >= tau) {
                unsigned int pos = atomicAdd(counter, 1u);
                if (pos < CAP) { cscore[pos] = s; cidx[pos] = 4*g + j; }
            }
        }
    }
}

__global__ __launch_bounds__(1024)
void rcnn_rank(const float* __restrict__ cls, const float* __restrict__ bbox,
               const float* __restrict__ rois, const float* __restrict__ iminfo,
               const float* __restrict__ cscore, const int* __restrict__ cidx,
               const unsigned int* __restrict__ counter,
               float4* __restrict__ bxg, float* __restrict__ areag,
               float* __restrict__ prg, unsigned long long* __restrict__ maskg)
{
    __shared__ __align__(16) float s_s[CAP];
    __shared__ __align__(16) int   s_id[CAP];
    __shared__ int tid_[MAXC];
    __shared__ unsigned long long maskw[5];
    const int t  = threadIdx.x;
    const int NT = 1024;
    int M = (int)*counter; if (M > CAP) M = CAP;
    for (int i = t; i < M; i += NT)  { s_s[i] = cscore[i]; s_id[i] = cidx[i]; }
    for (int r = t; r < MAXC; r += NT) tid_[r] = -1;
    if (t < 5) maskw[t] = 0ull;
    __syncthreads();
    {
        const float4* sv = (const float4*)s_s;
        const int4*   dv = (const int4*)s_id;
        int M4 = M >> 2;
        for (int i = t; i < M; i += NT) {
            float si = s_s[i]; int di = s_id[i];
            int r = 0;
            for (int jj = 0; jj < M4; jj++) {
                float4 sj = sv[jj]; int4 dj = dv[jj];
                r += (sj.x > si) || (sj.x == si && dj.x < di);
                r += (sj.y > si) || (sj.y == si && dj.y < di);
                r += (sj.z > si) || (sj.z == si && dj.z < di);
                r += (sj.w > si) || (sj.w == si && dj.w < di);
            }
            for (int j = M4 << 2; j < M; j++) {
                float sj = s_s[j]; int dj = s_id[j];
                r += (sj > si) || (sj == si && dj < di);
            }
            if (r < MAXC) tid_[r] = di;
        }
    }
    __syncthreads();
    float Himg = iminfo[0], Wimg = iminfo[1];
    for (int r = t; r < MAXCP; r += NT) {
        int i = (r < MAXC) ? tid_[r] : -1;
        float4 bx = make_float4(0.0f, 0.0f, 0.0f, 0.0f);
        float ar = 0.0f;
        if (i >= 0) {
            float p0 = cls[5*i], p1 = cls[5*i+1], p2 = cls[5*i+2], p3 = cls[5*i+3], p4 = cls[5*i+4];
            prg[5*r+0]=p0; prg[5*r+1]=p1; prg[5*r+2]=p2; prg[5*r+3]=p3; prg[5*r+4]=p4;
            float m = p1; int a = 1;
            if (p2 > m) { m = p2; a = 2; }
            if (p3 > m) { m = p3; a = 3; }
            if (p4 > m) { m = p4; a = 4; }
            float4 d4 = ((const float4*)bbox)[5*i + a];
            float bx1, by1, bx2, by2;
            decode4(rois[5*i+1], rois[5*i+2], rois[5*i+3], rois[5*i+4], d4, Wimg, Himg, bx1, by1, bx2, by2);
            bx = make_float4(bx1, by1, bx2, by2);
            ar = (bx2-bx1)*(by2-by1);
            atomicOr(&maskw[r>>6], 1ull << (r & 63));
        }
        bxg[r] = bx; areag[r] = ar;
    }
    __syncthreads();
    if (t < 5) maskg[t] = maskw[t];
}

__global__ __launch_bounds__(64)
void rcnn_sup(const float4* __restrict__ bxg, const float* __restrict__ areag,
              const unsigned long long* __restrict__ maskg,
              unsigned long long* __restrict__ supg)
{
    __shared__ float4 bxs[MAXCP];
    __shared__ float  ars[MAXCP];
    const int t = threadIdx.x;
    for (int r = t; r < MAXCP; r += 64) { bxs[r] = bxg[r]; ars[r] = areag[r]; }
    __syncthreads();
    int task = blockIdx.x * 64 + t;
    if (task >= NTASK) return;
    int w = task / MAXC;
    int i = task - w * MAXC;
    unsigned long long bits = 0ull;
    int j0 = w << 6;
    if (j0 + 63 > i) {
        float4 bi = bxs[i];
        float areaA = ars[i];
        for (int b = 0; b < 64; b++) {
            int j = j0 + b;
            float4 bj = bxs[j];
            float lx = fmaxf(bi.x, bj.x), ly = fmaxf(bi.y, bj.y);
            float rx = fminf(bi.z, bj.z), ry = fminf(bi.w, bj.w);
            float iw = fmaxf(rx - lx, 0.0f), ih = fmaxf(ry - ly, 0.0f);
            float inter = iw * ih;
            float iou = inter / (areaA + ars[j] - inter);
            bits |= (iou > 0.5f) ? (1ull << b) : 0ull;
        }
        unsigned long long jgt = (i < j0) ? ~0ull
                              : ((i - j0) >= 63 ? 0ull : ~((1ull << (i - j0 + 1)) - 1ull));
        bits &= jgt & maskg[w];
    }
    supg[i*6 + w] = bits;
}

__global__ __launch_bounds__(1024)
void rcnn_scan(const float4* __restrict__ bxg, const float* __restrict__ prg,
               const unsigned long long* __restrict__ maskg,
               const unsigned long long* __restrict__ supg, float* __restrict__ out)
{
    __shared__ __align__(16) unsigned long long sup[MAXC*6];
    __shared__ unsigned long long maskw[5];
    __shared__ float orows[TOPN*10];
    __shared__ int   kept_list[TOPN];
    __shared__ int   s_kept;
    const int t  = threadIdx.x;
    const int NT = 1024;
    {
        const ulonglong2* sg2 = (const ulonglong2*)supg;
        ulonglong2* sl2 = (ulonglong2*)sup;
        for (int k = t; k < (MAXC*6)/2; k += NT) sl2[k] = sg2[k];
    }
    if (t < 5) maskw[t] = maskg[t];
    for (int k = t; k < TOPN*10; k += NT) orows[k] = 0.0f;
    __syncthreads();
    if (t == 0) {
        unsigned long long k0=maskw[0], k1=maskw[1], k2=maskw[2], k3=maskw[3], k4=maskw[4];
        int kept = 0;
        #define SCAN_WORD(W, KW)                                                   \
        if (kept < TOPN) {                                                         \
            unsigned long long donem = 0ull;                                       \
            for (;;) {                                                             \
                unsigned long long rem = (KW) & ~donem;                            \
                if (!rem) break;                                                   \
                int b = __builtin_ctzll(rem);                                      \
                int i = (W << 6) + b;                                              \
                kept_list[kept++] = i;                                             \
                if (kept >= TOPN) break;                                           \
                unsigned long long s0 = sup[i*6+0], s1 = sup[i*6+1],               \
                                   s2 = sup[i*6+2], s3 = sup[i*6+3],               \
                                   s4 = sup[i*6+4];                                \
                k0 &= ~s0; k1 &= ~s1; k2 &= ~s2; k3 &= ~s3; k4 &= ~s4;             \
                donem = (b == 63) ? ~0ull : ((2ull << b) - 1ull);                  \
            }                                                                      \
        }
        SCAN_WORD(0, k0)
        SCAN_WORD(1, k1)
        SCAN_WORD(2, k2)
        SCAN_WORD(3, k3)
        SCAN_WORD(4, k4)
        #undef SCAN_WORD
        s_kept = kept;
    }
    __syncthreads();
    int kept = s_kept;
    if (t < kept) {
        int r = kept_list[t];
        float4 bx = bxg[r];
        float* row = &orows[t*10];
        row[0] = 0.0f;
        row[1] = bx.x; row[2] = bx.y; row[3] = bx.z; row[4] = bx.w;
        row[5] = prg[5*r+0]; row[6] = prg[5*r+1]; row[7] = prg[5*r+2];
        row[8] = prg[5*r+3]; row[9] = prg[5*r+4];
    }
    __syncthreads();
    for (int k = t; k < TOPN*10; k += NT) out[k] = orows[k];
}

extern "C" void kernel_launch(void* const* d_in, const int* in_sizes, int n_in,
                              void* d_out, int out_size, void* d_ws, size_t ws_size,
                              hipStream_t stream)
{
    const float* cls    = (const float*)d_in[0];
    const float* bbox   = (const float*)d_in[1];
    const float* rois   = (const float*)d_in[2];
    const float* iminfo = (const float*)d_in[3];
    int N  = in_sizes[0] / 5;
    int Ng = N / 4;  // N = 1e6, divisible by 4; Ng = 250000 <= NBLK*NTHR

    char*  ws   = (char*)d_ws;
    float* outp = (float*)d_out;

    // ---- preferred path: single cooperative kernel ----
    void* args[] = { (void*)&cls, (void*)&bbox, (void*)&rois, (void*)&iminfo,
                     (void*)&ws, (void*)&outp, (void*)&Ng };
    hipError_t e = hipLaunchCooperativeKernel((void*)rcnn_mega, dim3(NBLK), dim3(NTHR),
                                              args, 0, stream);
    if (e == hipSuccess) return;
    (void)hipGetLastError();   // clear sticky error, fall back

    // ---- fallback: proven round-4 7-kernel pipeline ----
    float* scores = (float*)ws;
    size_t off = ((size_t)N * 4 + 255) & ~(size_t)255;
    unsigned int* hist    = (unsigned int*)(ws + off); off += NBINS * 4;
    int*          taubin  = (int*)(ws + off);          off += 256;
    unsigned int* counter = (unsigned int*)(ws + off); off += 256;
    float*        cscore  = (float*)(ws + off);        off += CAP * 4;
    int*          cidx    = (int*)(ws + off);          off += CAP * 4;
    float4*       bxg     = (float4*)(ws + off);       off += MAXCP * 16;
    float*        areag   = (float*)(ws + off);        off += ((MAXCP * 4 + 255) & ~(size_t)255);
    float*        prg     = (float*)(ws + off);        off += ((MAXC * 5 * 4 + 255) & ~(size_t)255);
    unsigned long long* maskg = (unsigned long long*)(ws + off); off += 256;
    unsigned long long* supg  = (unsigned long long*)(ws + off); off += MAXC * 6 * 8;

    int blocksG = (Ng + 255) / 256;
    rcnn_pass1<<<blocksG, 256, 0, stream>>>((const float4*)cls, (const float4*)bbox,
                                            (const float4*)rois, iminfo,
                                            (float4*)scores, hist, counter, Ng);
    rcnn_hist<<<64, 1024, 0, stream>>>((const float4*)scores, hist, Ng);
    rcnn_pass2<<<1, 64, 0, stream>>>(hist, taubin);
    rcnn_pass3<<<blocksG, 256, 0, stream>>>((const float4*)scores, taubin,
                                            cscore, cidx, counter, Ng);
    rcnn_rank<<<1, 1024, 0, stream>>>(cls, bbox, rois, iminfo,
                                      cscore, cidx, counter,
                                      bxg, areag, prg, maskg);
    rcnn_sup<<<(NTASK + 63) / 64, 64, 0, stream>>>(bxg, areag, maskg, supg);
    rcnn_scan<<<1, 1024, 0, stream>>>(bxg, prg, maskg, supg, outp);
}

// Round 6
// 220.417 us; speedup vs baseline: 3.3673x; 3.3673x over previous
//
#include <hip/hip_runtime.h>
#include <math.h>

#define NBINS 4096
#define CAP   4096
#define MAXC  300
#define MAXCP 320
#define NTASK (MAXC*5)
#define TOPN  100

// Shared box-decode; expression-identical to previous rounds (absmax was 0.0).
__device__ __forceinline__ void decode4(float x1, float y1, float x2, float y2,
                                        float4 d4, float Wimg, float Himg,
                                        float& bx1, float& by1, float& bx2, float& by2)
{
    float w  = x2 - x1 + 1.0f;
    float h  = y2 - y1 + 1.0f;
    float cx = x1 + 0.5f*(w - 1.0f);
    float cy = y1 + 0.5f*(h - 1.0f);
    float d0 = d4.x*0.1f, d1 = d4.y*0.1f, d2 = d4.z*0.2f, d3 = d4.w*0.2f;
    float pcx = d0*w + cx;
    float pcy = d1*h + cy;
    float pw  = expf(d2)*w;
    float ph  = expf(d3)*h;
    bx1 = fminf(fmaxf(pcx - 0.5f*(pw-1.0f), 0.0f), Wimg-1.0f);
    by1 = fminf(fmaxf(pcy - 0.5f*(ph-1.0f), 0.0f), Himg-1.0f);
    bx2 = fminf(fmaxf(pcx + 0.5f*(pw-1.0f), 0.0f), Wimg-1.0f);
    by2 = fminf(fmaxf(pcy + 0.5f*(ph-1.0f), 0.0f), Himg-1.0f);
}

// first set bit index >= from across 5 named 64-bit words (bits 0..319), else MAXC.
// Named words (no dynamic register indexing -> no scratch).
__device__ __forceinline__ int nb5(unsigned long long k0, unsigned long long k1,
                                   unsigned long long k2, unsigned long long k3,
                                   unsigned long long k4, int from)
{
    if (from >= MAXC) return MAXC;
    int w = from >> 6;
    unsigned long long first = ~0ull << (from & 63);
    if (w <= 0) { unsigned long long m = k0 & (w == 0 ? first : ~0ull); if (m) return       __builtin_ctzll(m); }
    if (w <= 1) { unsigned long long m = k1 & (w == 1 ? first : ~0ull); if (m) return  64 + __builtin_ctzll(m); }
    if (w <= 2) { unsigned long long m = k2 & (w == 2 ? first : ~0ull); if (m) return 128 + __builtin_ctzll(m); }
    if (w <= 3) { unsigned long long m = k3 & (w == 3 ? first : ~0ull); if (m) return 192 + __builtin_ctzll(m); }
    {           unsigned long long m = k4 & (w == 4 ? first : ~0ull); if (m) return 256 + __builtin_ctzll(m); }
    return MAXC;
}

// ---------------- pass 1: 4 ROIs/thread, float4 loads, scores only (NO atomics) ----------------
__global__ __launch_bounds__(256)
void rcnn_pass1(const float4* __restrict__ cls4, const float4* __restrict__ bbox4,
                const float4* __restrict__ rois4, const float* __restrict__ iminfo,
                float4* __restrict__ scores4,
                unsigned int* __restrict__ hist, unsigned int* __restrict__ counter, int Ng)
{
    if (blockIdx.x == 0) {
        for (int k = threadIdx.x; k < NBINS; k += 256) hist[k] = 0u;
        if (threadIdx.x == 0) *counter = 0u;
    }
    int g = blockIdx.x * blockDim.x + threadIdx.x;
    if (g >= Ng) return;
    float c[20], q[20];
    #pragma unroll
    for (int v = 0; v < 5; v++) {
        float4 cv = cls4[5*g + v];
        c[4*v] = cv.x; c[4*v+1] = cv.y; c[4*v+2] = cv.z; c[4*v+3] = cv.w;
        float4 rv = rois4[5*g + v];
        q[4*v] = rv.x; q[4*v+1] = rv.y; q[4*v+2] = rv.z; q[4*v+3] = rv.w;
    }
    float Himg = iminfo[0], Wimg = iminfo[1];
    float s[4];
    #pragma unroll
    for (int j = 0; j < 4; j++) {
        float p0 = c[5*j], p1 = c[5*j+1], p2 = c[5*j+2], p3 = c[5*j+3], p4 = c[5*j+4];
        float m = p1; int a = 1;
        if (p2 > m) { m = p2; a = 2; }
        if (p3 > m) { m = p3; a = 3; }
        if (p4 > m) { m = p4; a = 4; }
        float sc = -1.0f;
        if (((1.0f - p0) >= 0.2f) && (m > 0.1f)) {
            float4 d4 = bbox4[20*g + 5*j + a];
            float bx1, by1, bx2, by2;
            decode4(q[5*j+1], q[5*j+2], q[5*j+3], q[5*j+4], d4, Wimg, Himg, bx1, by1, bx2, by2);
            float bw = bx2 - bx1 + 1.0f;
            float bh = by2 - by1 + 1.0f;
            if ((bw >= 6.0f) || (bh >= 6.0f)) sc = m;
        }
        s[j] = sc;
    }
    scores4[g] = make_float4(s[0], s[1], s[2], s[3]);
}

// ---------------- pass 1b: LDS histogram over scores (few blocks, coalesced flush) ----------------
__global__ __launch_bounds__(1024)
void rcnn_hist(const float4* __restrict__ scores4, unsigned int* __restrict__ hist, int Ng)
{
    __shared__ unsigned int lh[NBINS];
    const int t = threadIdx.x;
    for (int k = t; k < NBINS; k += 1024) lh[k] = 0u;
    __syncthreads();
    int stride = gridDim.x * 1024;
    for (int g = blockIdx.x * 1024 + t; g < Ng; g += stride) {
        float4 s4 = scores4[g];
        float ss[4] = { s4.x, s4.y, s4.z, s4.w };
        #pragma unroll
        for (int j = 0; j < 4; j++) {
            float s = ss[j];
            if (s > -0.5f) {
                int bin = (int)(s * (float)NBINS);
                bin = bin > NBINS-1 ? NBINS-1 : bin;
                atomicAdd(&lh[bin], 1u);
            }
        }
    }
    __syncthreads();
    for (int k = t; k < NBINS; k += 1024) {
        unsigned int v = lh[k];
        if (v) atomicAdd(&hist[k], v);
    }
}

// ---------------- pass 3+tau: per-block redundant tau (wave 0) + compact candidates ----------------
// tau = largest bin with suffix_count >= MAXC, else 0 — bit-identical to the proven rcnn_pass2.
__global__ __launch_bounds__(256)
void rcnn_pass3t(const float4* __restrict__ scores4, const unsigned int* __restrict__ hist,
                 float* __restrict__ cscore, int* __restrict__ cidx,
                 unsigned int* __restrict__ counter, int Ng)
{
    __shared__ int s_tau;
    const int t = threadIdx.x;
    if (t < 64) {   // wave 0 computes tau from the completed global hist (L2-hot 16 KB)
        const uint4* h4 = (const uint4*)hist;
        uint4 v[16];
        #pragma unroll
        for (int j = 0; j < 16; j++) v[j] = h4[t*16 + j];   // lane t owns bins [64t, 64t+64)
        unsigned int chunk = 0;
        #pragma unroll
        for (int j = 0; j < 16; j++) chunk += v[j].x + v[j].y + v[j].z + v[j].w;
        unsigned int sfx = chunk;   // inclusive suffix-sum across 64 lanes
        #pragma unroll
        for (int d = 1; d < 64; d <<= 1) {
            unsigned int o = __shfl_down(sfx, d, 64);
            if (t + d < 64) sfx += o;
        }
        unsigned int nxt = sfx - chunk;
        bool found = (sfx >= MAXC) && (nxt < MAXC);   // unique boundary lane (suffix monotone)
        unsigned long long bal = __ballot(found);
        if (found) {
            unsigned int cum = nxt;
            int tauv = 64*t;
            #pragma unroll
            for (int k = 15; k >= 0; k--) {
                cum += v[k].w; if (cum >= MAXC) { tauv = 64*t + 4*k + 3; goto dtau; }
                cum += v[k].z; if (cum >= MAXC) { tauv = 64*t + 4*k + 2; goto dtau; }
                cum += v[k].y; if (cum >= MAXC) { tauv = 64*t + 4*k + 1; goto dtau; }
                cum += v[k].x; if (cum >= MAXC) { tauv = 64*t + 4*k + 0; goto dtau; }
            }
            dtau:
            s_tau = tauv;
        }
        if (bal == 0ull && t == 0) s_tau = 0;
    }
    __syncthreads();
    int tau = s_tau;

    int g = blockIdx.x * blockDim.x + t;
    if (g >= Ng) return;
    float4 s4 = scores4[g];
    float ss[4] = { s4.x, s4.y, s4.z, s4.w };
    #pragma unroll
    for (int j = 0; j < 4; j++) {
        float s = ss[j];
        if (s > -0.5f) {
            int bin = (int)(s * (float)NBINS);
            bin = bin > NBINS-1 ? NBINS-1 : bin;
            if (bin >= tau) {
                unsigned int pos = atomicAdd(counter, 1u);
                if (pos < CAP) { cscore[pos] = s; cidx[pos] = 4*g + j; }
            }
        }
    }
}

// ---------------- rank: exact stable top-300 rank + decode (1 block) ----------------
__global__ __launch_bounds__(1024)
void rcnn_rank(const float* __restrict__ cls, const float* __restrict__ bbox,
               const float* __restrict__ rois, const float* __restrict__ iminfo,
               const float* __restrict__ cscore, const int* __restrict__ cidx,
               const unsigned int* __restrict__ counter,
               float4* __restrict__ bxg, float* __restrict__ areag,
               float* __restrict__ prg, unsigned long long* __restrict__ maskg)
{
    __shared__ __align__(16) float s_s[CAP];
    __shared__ __align__(16) int   s_id[CAP];
    __shared__ int tid_[MAXC];
    __shared__ unsigned long long maskw[5];
    const int t  = threadIdx.x;
    const int NT = 1024;
    int M = (int)*counter; if (M > CAP) M = CAP;
    for (int i = t; i < M; i += NT)  { s_s[i] = cscore[i]; s_id[i] = cidx[i]; }
    for (int r = t; r < MAXC; r += NT) tid_[r] = -1;
    if (t < 5) maskw[t] = 0ull;
    __syncthreads();

    // exact stable rank: (score desc, index asc) == jax.lax.top_k order; b128 LDS reads
    {
        const float4* sv = (const float4*)s_s;
        const int4*   dv = (const int4*)s_id;
        int M4 = M >> 2;
        for (int i = t; i < M; i += NT) {
            float si = s_s[i]; int di = s_id[i];
            int r = 0;
            for (int jj = 0; jj < M4; jj++) {
                float4 sj = sv[jj]; int4 dj = dv[jj];
                r += (sj.x > si) || (sj.x == si && dj.x < di);
                r += (sj.y > si) || (sj.y == si && dj.y < di);
                r += (sj.z > si) || (sj.z == si && dj.z < di);
                r += (sj.w > si) || (sj.w == si && dj.w < di);
            }
            for (int j = M4 << 2; j < M; j++) {
                float sj = s_s[j]; int dj = s_id[j];
                r += (sj > si) || (sj == si && dj < di);
            }
            if (r < MAXC) tid_[r] = di;
        }
    }
    __syncthreads();

    // decode boxes + gather probs for the ranked 300; precompute areas; validity mask
    float Himg = iminfo[0], Wimg = iminfo[1];
    for (int r = t; r < MAXCP; r += NT) {
        int i = (r < MAXC) ? tid_[r] : -1;
        float4 bx = make_float4(0.0f, 0.0f, 0.0f, 0.0f);
        float ar = 0.0f;
        if (i >= 0) {
            float p0 = cls[5*i], p1 = cls[5*i+1], p2 = cls[5*i+2], p3 = cls[5*i+3], p4 = cls[5*i+4];
            prg[5*r+0]=p0; prg[5*r+1]=p1; prg[5*r+2]=p2; prg[5*r+3]=p3; prg[5*r+4]=p4;
            float m = p1; int a = 1;
            if (p2 > m) { m = p2; a = 2; }
            if (p3 > m) { m = p3; a = 3; }
            if (p4 > m) { m = p4; a = 4; }
            float4 d4 = ((const float4*)bbox)[5*i + a];
            float bx1, by1, bx2, by2;
            decode4(rois[5*i+1], rois[5*i+2], rois[5*i+3], rois[5*i+4], d4, Wimg, Himg, bx1, by1, bx2, by2);
            bx = make_float4(bx1, by1, bx2, by2);
            ar = (bx2-bx1)*(by2-by1);
            atomicOr(&maskw[r>>6], 1ull << (r & 63));
        }
        bxg[r] = bx; areag[r] = ar;
    }
    __syncthreads();
    if (t < 5) maskg[t] = maskw[t];
}

// ---------------- sup: suppression bitmask matrix, parallel across CUs (1 wave/block) ----------------
__global__ __launch_bounds__(64)
void rcnn_sup(const float4* __restrict__ bxg, const float* __restrict__ areag,
              const unsigned long long* __restrict__ maskg,
              unsigned long long* __restrict__ supg)
{
    __shared__ float4 bxs[MAXCP];
    __shared__ float  ars[MAXCP];
    const int t = threadIdx.x;
    for (int r = t; r < MAXCP; r += 64) { bxs[r] = bxg[r]; ars[r] = areag[r]; }
    __syncthreads();
    int task = blockIdx.x * 64 + t;
    if (task >= NTASK) return;
    int w = task / MAXC;
    int i = task - w * MAXC;
    unsigned long long bits = 0ull;
    int j0 = w << 6;
    if (j0 + 63 > i) {
        float4 bi = bxs[i];
        float areaA = ars[i];
        // IEEE division kept on purpose: bit-exact keep-mask vs the JAX reference.
        for (int b = 0; b < 64; b++) {
            int j = j0 + b;
            float4 bj = bxs[j];
            float lx = fmaxf(bi.x, bj.x), ly = fmaxf(bi.y, bj.y);
            float rx = fminf(bi.z, bj.z), ry = fminf(bi.w, bj.w);
            float iw = fmaxf(rx - lx, 0.0f), ih = fmaxf(ry - ly, 0.0f);
            float inter = iw * ih;
            float iou = inter / (areaA + ars[j] - inter);  // NaN/neg-safe: compare false
            bits |= (iou > 0.5f) ? (1ull << b) : 0ull;
        }
        unsigned long long jgt = (i < j0) ? ~0ull
                              : ((i - j0) >= 63 ? 0ull : ~((1ull << (i - j0 + 1)) - 1ull));
        bits &= jgt & maskg[w];
    }
    supg[i*6 + w] = bits;   // row stride 6 (48B) -> rows 16B-aligned for b128 loads in scan
}

// ---------------- scan: serial greedy NMS (ctz + speculative row prefetch) + output (1 block) ----------------
__global__ __launch_bounds__(1024)
void rcnn_scan(const float4* __restrict__ bxg, const float* __restrict__ prg,
               const unsigned long long* __restrict__ maskg,
               const unsigned long long* __restrict__ supg, float* __restrict__ out)
{
    __shared__ __align__(16) unsigned long long sup[MAXC*6];
    __shared__ float orows[TOPN*10];
    __shared__ int   kept_list[TOPN];
    __shared__ int   s_kept;
    const int t  = threadIdx.x;
    const int NT = 1024;

    // cooperative sup -> LDS (900 x b128)
    {
        const ulonglong2* sg2 = (const ulonglong2*)supg;
        ulonglong2* sl2 = (ulonglong2*)sup;
        for (int k = t; k < (MAXC*6)/2; k += NT) sl2[k] = sg2[k];
    }
    for (int k = t; k < TOPN*10; k += NT) orows[k] = 0.0f;
    __syncthreads();

    // serial greedy scan, EXACT early stop at the 100th kept box (suppression only
    // flows to j>i; output reads only the first TOPN kept). Speculation: the next
    // alive bit post-AND almost always equals the next set bit pre-AND, so prefetch
    // that row in the same issue window; on a miss, load fresh (semantics identical).
    if (t == 0) {
        unsigned long long k0=maskg[0], k1=maskg[1], k2=maskg[2], k3=maskg[3], k4=maskg[4];
        int kept = 0;
        int specp = -1;
        unsigned long long h0=0ull,h1=0ull,h2=0ull,h3=0ull,h4=0ull;
        int cur = nb5(k0,k1,k2,k3,k4, 0);
        while (cur < MAXC && kept < TOPN) {
            kept_list[kept++] = cur;
            if (kept >= TOPN) break;
            unsigned long long r0,r1,r2,r3,r4;
            if (cur == specp) { r0=h0; r1=h1; r2=h2; r3=h3; r4=h4; }
            else {
                const ulonglong2* rp = (const ulonglong2*)&sup[cur*6];
                ulonglong2 ra = rp[0], rb = rp[1];
                r0=ra.x; r1=ra.y; r2=rb.x; r3=rb.y; r4=sup[cur*6+4];
            }
            int spec = nb5(k0,k1,k2,k3,k4, cur+1);   // pre-AND guess of next alive bit
            if (spec < MAXC) {
                const ulonglong2* sp = (const ulonglong2*)&sup[spec*6];
                ulonglong2 sa = sp[0], sb = sp[1];
                h0=sa.x; h1=sa.y; h2=sb.x; h3=sb.y; h4=sup[spec*6+4];
                specp = spec;
            } else specp = -1;
            k0 &= ~r0; k1 &= ~r1; k2 &= ~r2; k3 &= ~r3; k4 &= ~r4;
            cur = nb5(k0,k1,k2,k3,k4, cur+1);        // true next alive bit
        }
        s_kept = kept;
    }
    __syncthreads();

    int kept = s_kept;
    if (t < kept) {
        int r = kept_list[t];
        float4 bx = bxg[r];
        float* row = &orows[t*10];
        row[0] = 0.0f;
        row[1] = bx.x; row[2] = bx.y; row[3] = bx.z; row[4] = bx.w;
        row[5] = prg[5*r+0]; row[6] = prg[5*r+1]; row[7] = prg[5*r+2];
        row[8] = prg[5*r+3]; row[9] = prg[5*r+4];
    }
    __syncthreads();
    for (int k = t; k < TOPN*10; k += NT) out[k] = orows[k];
}

extern "C" void kernel_launch(void* const* d_in, const int* in_sizes, int n_in,
                              void* d_out, int out_size, void* d_ws, size_t ws_size,
                              hipStream_t stream)
{
    const float* cls    = (const float*)d_in[0];
    const float* bbox   = (const float*)d_in[1];
    const float* rois   = (const float*)d_in[2];
    const float* iminfo = (const float*)d_in[3];
    int N  = in_sizes[0] / 5;
    int Ng = N / 4;  // N = 1e6, divisible by 4

    char* ws = (char*)d_ws;
    float* scores = (float*)ws;
    size_t off = ((size_t)N * 4 + 255) & ~(size_t)255;
    unsigned int* hist    = (unsigned int*)(ws + off); off += NBINS * 4;
    int*          taubin  = (int*)(ws + off);          off += 256;  (void)taubin;
    unsigned int* counter = (unsigned int*)(ws + off); off += 256;
    float*        cscore  = (float*)(ws + off);        off += CAP * 4;
    int*          cidx    = (int*)(ws + off);          off += CAP * 4;
    float4*       bxg     = (float4*)(ws + off);       off += MAXCP * 16;
    float*        areag   = (float*)(ws + off);        off += ((MAXCP * 4 + 255) & ~(size_t)255);
    float*        prg     = (float*)(ws + off);        off += ((MAXC * 5 * 4 + 255) & ~(size_t)255);
    unsigned long long* maskg = (unsigned long long*)(ws + off); off += 256;
    unsigned long long* supg  = (unsigned long long*)(ws + off); off += MAXC * 6 * 8;

    int blocksG = (Ng + 255) / 256;
    rcnn_pass1<<<blocksG, 256, 0, stream>>>((const float4*)cls, (const float4*)bbox,
                                            (const float4*)rois, iminfo,
                                            (float4*)scores, hist, counter, Ng);
    rcnn_hist<<<64, 1024, 0, stream>>>((const float4*)scores, hist, Ng);
    rcnn_pass3t<<<blocksG, 256, 0, stream>>>((const float4*)scores, hist,
                                             cscore, cidx, counter, Ng);
    rcnn_rank<<<1, 1024, 0, stream>>>(cls, bbox, rois, iminfo,
                                      cscore, cidx, counter,
                                      bxg, areag, prg, maskg);
    rcnn_sup<<<(NTASK + 63) / 64, 64, 0, stream>>>(bxg, areag, maskg, supg);
    rcnn_scan<<<1, 1024, 0, stream>>>(bxg, prg, maskg, supg, (float*)d_out);
}